// Round 8
// baseline (876.803 us; speedup 1.0000x reference)
//
#include <hip/hip_runtime.h>
#include <math.h>

#define NN 10000
#define NE 160000
#define NG 64
#define FEAT 80
#define NT 5
#define NL 4

// ---------------- setup kernels ----------------
__global__ void k_cnt2(const int* __restrict__ dst, const int* __restrict__ batch,
                       int* __restrict__ deg, int* __restrict__ gcnt) {
    int e = blockIdx.x * 256 + threadIdx.x;
    if (e < NE) atomicAdd(&deg[dst[e]], 1);
    if (e < NN) atomicAdd(&gcnt[batch[e]], 1);
}

__global__ void k_scan(const int* __restrict__ deg, int* __restrict__ offs) {
    __shared__ int sums[256];
    int tid = threadIdx.x;
    int start = tid * 40, stop = min(start + 40, NN);
    int s = 0;
    for (int i = start; i < stop; ++i) s += deg[i];
    sums[tid] = s;
    __syncthreads();
    for (int off = 1; off < 256; off <<= 1) {
        int v = (tid >= off) ? sums[tid - off] : 0;
        __syncthreads();
        sums[tid] += v;
        __syncthreads();
    }
    int base = (tid == 0) ? 0 : sums[tid - 1];
    for (int i = start; i < stop; ++i) { offs[i] = base; base += deg[i]; }
    if (tid == 255) offs[NN] = sums[255];
}

__global__ void k_ald(const int* __restrict__ deg, float* __restrict__ ald) {
    __shared__ float red[256];
    int i = blockIdx.x * 256 + threadIdx.x;
    red[threadIdx.x] = (i < NN) ? logf((float)deg[i] + 1.0f) : 0.0f;
    __syncthreads();
    for (int s = 128; s > 0; s >>= 1) {
        if (threadIdx.x < s) red[threadIdx.x] += red[threadIdx.x + s];
        __syncthreads();
    }
    if (threadIdx.x == 0) atomicAdd(ald, red[0]);
}

__global__ void k_fill(const int* __restrict__ src, const int* __restrict__ dst,
                       const int* __restrict__ offs, int* __restrict__ cursor,
                       int* __restrict__ csr) {
    int e = blockIdx.x * 256 + threadIdx.x;
    if (e < NE) {
        int d = dst[e];
        int p = atomicAdd(&cursor[d], 1);
        csr[offs[d] + p] = src[e];
    }
}

// hT is feature-major: hT[f*NN + n]
__global__ void k_op0(const float* __restrict__ x, const float* __restrict__ plW,
                      const float* __restrict__ plb, float* __restrict__ hT) {
    int i = blockIdx.x * 256 + threadIdx.x;  // i = f*NN + n
    if (i < FEAT * NN) {
        int f = i / NN, n = i - f * NN;
        hT[i] = x[2 * n] * plW[f] + plb[f];
    }
}

// ---------------- per-layer kernels ----------------
// k_mm_ab v3 (R6-proven): 4 c-slots per thread, grid (625). 16 FMA per
// block-broadcast ds_read_b128 (was 8 in v2 at 45us).
// A[n][c] (c = t*80+o, c<400) = sum_f h[n][f] * preW[t][f][o]        (dst half)
// Bt[t][n][o]                 = sum_f h[n][f] * preW[t][80+f][o]     (src half)
__global__ __launch_bounds__(256) void k_mm_ab(
        const float* __restrict__ hT, const float* __restrict__ preW_l,
        float* __restrict__ A, float* __restrict__ Bt) {
    __shared__ float hs[16][80];
    int n0 = blockIdx.x * 16;
    int tid = threadIdx.x;
    for (int i = tid; i < 16 * 80; i += 256) {
        int nl = i & 15, f = i >> 4;
        hs[nl][f] = hT[(size_t)f * NN + n0 + nl];
    }
    __syncthreads();
    float acc[4][16];
#pragma unroll
    for (int s = 0; s < 4; s++)
#pragma unroll
        for (int i = 0; i < 16; i++) acc[s][i] = 0.f;
    const float* wp[4];
#pragma unroll
    for (int s = 0; s < 4; s++) {
        int c = tid + s * 256;
        int cs = (c < 800) ? c : 0;          // safe base for dead slots
        int part = (cs >= 400) ? 1 : 0;
        int cc = cs - part * 400;
        int t = cc / 80, o = cc - t * 80;
        wp[s] = preW_l + (size_t)(t * 160 + part * 80) * 80 + o;  // + f*80 per f
    }
    for (int fq = 0; fq < 80; fq += 4) {
        float w[4][4];
#pragma unroll
        for (int s = 0; s < 4; s++) {
            w[s][0] = wp[s][(fq + 0) * 80];
            w[s][1] = wp[s][(fq + 1) * 80];
            w[s][2] = wp[s][(fq + 2) * 80];
            w[s][3] = wp[s][(fq + 3) * 80];
        }
#pragma unroll
        for (int i = 0; i < 16; i++) {
            float4 hv = *(const float4*)&hs[i][fq];
#pragma unroll
            for (int s = 0; s < 4; s++) {
                acc[s][i] += hv.x * w[s][0] + hv.y * w[s][1] +
                             hv.z * w[s][2] + hv.w * w[s][3];
            }
        }
    }
#pragma unroll
    for (int s = 0; s < 4; s++) {
        int c = tid + s * 256;
        if (c < 800) {
            int part = (c >= 400) ? 1 : 0;
            int cc = c - part * 400;
            int t = cc / 80, o = cc - t * 80;
            if (part == 0) {
#pragma unroll
                for (int i = 0; i < 16; i++) A[(size_t)(n0 + i) * 400 + cc] = acc[s][i];
            } else {
#pragma unroll
                for (int i = 0; i < 16; i++)
                    Bt[((size_t)t * NN + n0 + i) * 80 + o] = acc[s][i];
            }
        }
    }
}

// k_aggpost (R7 FUSION): k_agg_t + k_post in one kernel. Rationale: the agg
// block already holds the full 320-j agg vector for its 16 nodes in st[] —
// spilling it to aggT cost ~77MB HBM write (k_agg_t) + ~38MB HBM fetch
// (k_post) + 25MB y0T atomic writebacks + a memset, per layer.
// Phase 1 (gather): VERBATIM from R4/R6-proven k_agg_t (XCD t-clustering
// remap: FETCH 114.7 -> 57.3MB confirmed; each XCD serves <=2 t-slices).
// Phase 2 (post-GEMM): thread (ni=tid&15, og=(tid>>4)&3, js=tid>>6) owns
// 4 o x 3 parts over an 80-j slice. st reads: b32, 16 addr x 4-lane
// broadcast (conflict-free). Weights read from GLOBAL, not LDS (61KB staging
// would cap 1 block/CU and kill gather latency hiding): per wave each part
// read is one coalesced 64B dwordx4, L1-hot (shared by all 625 n-blocks of
// the t). js-partials reduced via the dead st buffer; 64 threads apply
// c1/c2/bias and write y0T DIRECTLY (block owns all j -> no atomics).
__global__ __launch_bounds__(256) void k_aggpost(
        const float* __restrict__ A, const float* __restrict__ Bt,
        const int* __restrict__ offs, const int* __restrict__ csr,
        const float* __restrict__ preb_l, const float* __restrict__ hT,
        const float* __restrict__ postW_l, const float* __restrict__ postb_l,
        const float* __restrict__ ald_sum, float* __restrict__ y0T) {
    __shared__ float st[320 * 17];   // 21.76 KB; reused as reduce buffer
    int tid = threadIdx.x;
    // ---- XCD remap: 3125 blocks = 5*391 + 3*390 ----
    int id = blockIdx.y * 625 + blockIdx.x;
    int xcd = id & 7;
    int slot = id >> 3;
    int base = (xcd <= 5) ? xcd * 391 : 5 * 391 + (xcd - 5) * 390;
    int r = base + slot;
    int t = r / 625;
    int n0 = (r - t * 625) * 16;
    // ---- phase 1: edge gather (proven k_agg_t body) ----
    int ni = tid >> 4;   // node within block
    int cl = tid & 15;   // c-lane
    int n = n0 + ni;
    int e0 = offs[n], e1 = offs[n + 1];
    const float* Bts = Bt + (size_t)t * NN * 80;
    float s[5], q[5], mn[5], mx[5];
#pragma unroll
    for (int k = 0; k < 5; k++) { s[k] = 0.f; q[k] = 0.f; mn[k] = 3.4e38f; mx[k] = -3.4e38f; }
    int e = e0;
    for (; e + 3 < e1; e += 4) {
        const float* br0 = Bts + (size_t)csr[e] * 80 + cl;
        const float* br1 = Bts + (size_t)csr[e + 1] * 80 + cl;
        const float* br2 = Bts + (size_t)csr[e + 2] * 80 + cl;
        const float* br3 = Bts + (size_t)csr[e + 3] * 80 + cl;
#pragma unroll
        for (int k = 0; k < 5; k++) {
            float b0 = br0[k * 16];
            float b1 = br1[k * 16];
            float b2 = br2[k * 16];
            float b3 = br3[k * 16];
            s[k] += (b0 + b1) + (b2 + b3);
            q[k] += (b0 * b0 + b1 * b1) + (b2 * b2 + b3 * b3);
            mn[k] = fminf(mn[k], fminf(fminf(b0, b1), fminf(b2, b3)));
            mx[k] = fmaxf(mx[k], fmaxf(fmaxf(b0, b1), fmaxf(b2, b3)));
        }
    }
    for (; e < e1; ++e) {
        const float* br = Bts + (size_t)csr[e] * 80 + cl;
#pragma unroll
        for (int k = 0; k < 5; k++) {
            float b = br[k * 16];
            s[k] += b; q[k] += b * b;
            mn[k] = fminf(mn[k], b); mx[k] = fmaxf(mx[k], b);
        }
    }
    int d = e1 - e0;
    float degf = (float)d;
    float cnt = fmaxf(degf, 1.f);
#pragma unroll
    for (int k = 0; k < 5; k++) {
        int c = cl + k * 16;
        float a = A[(size_t)n * 400 + t * 80 + c] + preb_l[t * 80 + c];
        float mean = (degf * a + s[k]) / cnt;
        float msq  = (degf * a * a + 2.f * a * s[k] + q[k]) / cnt;
        float sd = sqrtf(fmaxf(msq - mean * mean, 0.f) + 1e-5f);
        float mnr = (d > 0) ? a + mn[k] : 0.f;
        float mxr = (d > 0) ? a + mx[k] : 0.f;
        st[(0 * 80 + c) * 17 + ni] = mean;
        st[(1 * 80 + c) * 17 + ni] = mnr;
        st[(2 * 80 + c) * 17 + ni] = mxr;
        st[(3 * 80 + c) * 17 + ni] = sd;
    }
    __syncthreads();
    // ---- phase 2: post-GEMM ----
    int ni2 = tid & 15;         // node
    int og  = (tid >> 4) & 3;   // o-quad
    int js  = tid >> 6;         // j/f slice (= wave index)
    const float* W0 = postW_l + (size_t)t * 1040 * 16;
    float a1[4], a2[4], a3[4];
#pragma unroll
    for (int i = 0; i < 4; i++) { a1[i] = 0.f; a2[i] = 0.f; a3[i] = 0.f; }
    int jb = js * 80;
#pragma unroll 2
    for (int j = jb; j < jb + 80; ++j) {
        float a = st[j * 17 + ni2];
        float4 w1 = *(const float4*)(W0 + (size_t)(80 + j) * 16 + og * 4);
        float4 w2 = *(const float4*)(W0 + (size_t)(400 + j) * 16 + og * 4);
        float4 w3 = *(const float4*)(W0 + (size_t)(720 + j) * 16 + og * 4);
        a1[0] += a * w1.x; a1[1] += a * w1.y; a1[2] += a * w1.z; a1[3] += a * w1.w;
        a2[0] += a * w2.x; a2[1] += a * w2.y; a2[2] += a * w2.z; a2[3] += a * w2.w;
        a3[0] += a * w3.x; a3[1] += a * w3.y; a3[2] += a * w3.z; a3[3] += a * w3.w;
    }
    // h-part (xt block of postW), f split across js
    int fb = js * 20;
#pragma unroll 2
    for (int f = fb; f < fb + 20; ++f) {
        float hv = hT[(size_t)f * NN + n0 + ni2];
        float4 w0 = *(const float4*)(W0 + (size_t)f * 16 + og * 4);
        a1[0] += hv * w0.x; a1[1] += hv * w0.y; a1[2] += hv * w0.z; a1[3] += hv * w0.w;
    }
    __syncthreads();            // all st reads done; st becomes reduce buffer
    float* red = st;
#pragma unroll
    for (int i = 0; i < 4; i++) {
        red[tid * 12 + i]     = a1[i];
        red[tid * 12 + 4 + i] = a2[i];
        red[tid * 12 + 8 + i] = a3[i];
    }
    __syncthreads();
    if (tid < 64) {
        int ni3 = tid & 15, og3 = tid >> 4;
        float b1[4], b2[4], b3[4];
#pragma unroll
        for (int i = 0; i < 4; i++) { b1[i] = 0.f; b2[i] = 0.f; b3[i] = 0.f; }
#pragma unroll
        for (int js3 = 0; js3 < 4; ++js3) {
            const float* rr = red + (size_t)(ni3 + 16 * (og3 + 4 * js3)) * 12;
#pragma unroll
            for (int i = 0; i < 4; i++) {
                b1[i] += rr[i]; b2[i] += rr[4 + i]; b3[i] += rr[8 + i];
            }
        }
        int nw = n0 + ni3;
        float dw = (float)(offs[nw + 1] - offs[nw]);
        float ald = ald_sum[0] * (1.f / NN);
        float logd = logf(fmaxf(dw, 1.f) + 1.f);
        float c1 = logd / ald;
        float c2 = ald / logd;
#pragma unroll
        for (int i = 0; i < 4; i++) {
            int o = og3 * 4 + i;
            float v = b1[i] + c1 * b2[i] + c2 * b3[i] + postb_l[t * 16 + o];
            y0T[(size_t)(t * 16 + o) * NN + nw] = v;
        }
    }
}

// k_lin v2 (R8-proven): grid (40, 10), 8 f per block, weights LDS-staged.
// yT[f][n] = sum_k y0T[k][n] * linW[k][f] + linb[f]
__global__ __launch_bounds__(256) void k_lin(
        const float* __restrict__ y0T, const float* __restrict__ linW_l,
        const float* __restrict__ linb_l, float* __restrict__ yT) {
    __shared__ float ws[80 * 8];  // 2.56 KB
    int tid = threadIdx.x;
    int f0 = blockIdx.y * 8;
    for (int idx = tid; idx < 80 * 8; idx += 256)
        ws[idx] = linW_l[(idx >> 3) * 80 + f0 + (idx & 7)];
    __syncthreads();
    int n = blockIdx.x * 256 + tid;
    bool alive = (n < NN);
    int nc = alive ? n : 0;
    float acc[8];
#pragma unroll
    for (int i = 0; i < 8; i++) acc[i] = 0.f;
#pragma unroll 8
    for (int k = 0; k < 80; ++k) {
        float v = y0T[(size_t)k * NN + nc];
        const float4 wa = *(const float4*)(ws + k * 8);
        const float4 wb = *(const float4*)(ws + k * 8 + 4);
        acc[0] += v * wa.x; acc[1] += v * wa.y; acc[2] += v * wa.z; acc[3] += v * wa.w;
        acc[4] += v * wb.x; acc[5] += v * wb.y; acc[6] += v * wb.z; acc[7] += v * wb.w;
    }
    if (alive) {
#pragma unroll
        for (int i = 0; i < 8; i++)
            yT[(size_t)(f0 + i) * NN + n] = acc[i] + linb_l[f0 + i];
    }
}

// k_bnstats v2: grid (80, 8). Each block reduces a 1250-node segment of one f;
// 2 fp32 atomics into launch-zeroed bnst.
__global__ void k_bnstats(const float* __restrict__ yT, float* __restrict__ bnst) {
    __shared__ float r1[256], r2[256];
    int f = blockIdx.x;
    int seg = blockIdx.y;
    int tid = threadIdx.x;
    int i0 = seg * 1250, i1 = min(i0 + 1250, NN);
    float s = 0.f, q = 0.f;
    for (int i = i0 + tid; i < i1; i += 256) {
        float v = yT[(size_t)f * NN + i];
        s += v; q += v * v;
    }
    r1[tid] = s; r2[tid] = q;
    __syncthreads();
    for (int st = 128; st > 0; st >>= 1) {
        if (tid < st) { r1[tid] += r1[tid + st]; r2[tid] += r2[tid + st]; }
        __syncthreads();
    }
    if (tid == 0) {
        unsafeAtomicAdd(&bnst[f], r1[0]);
        unsafeAtomicAdd(&bnst[80 + f], r2[0]);
    }
}

__global__ void k_bn(const float* __restrict__ yT, const float* __restrict__ bnst,
                     const float* __restrict__ gamma_l, const float* __restrict__ beta_l,
                     float* __restrict__ hT) {
    int i = blockIdx.x * 256 + threadIdx.x;
    if (i >= FEAT * NN) return;
    int f = i / NN;
    float mu = bnst[f] * (1.f / NN);
    float msq = bnst[80 + f] * (1.f / NN);
    float var = fmaxf(msq - mu * mu, 0.f);
    float v = (yT[i] - mu) * (1.f / sqrtf(var + 1e-5f)) * gamma_l[f] + beta_l[f];
    hT[i] = fmaxf(v, 0.f);
}

// Last layer: fused bn + relu + xc + log. Thread handles (f, n) with f in
// [0,40); computes bn for f and f+40, writes lxc directly (hT is dead).
__global__ void k_bnxc(const float* __restrict__ yT, const float* __restrict__ bnst,
                       const float* __restrict__ gamma_l, const float* __restrict__ beta_l,
                       const float* __restrict__ x, float* __restrict__ lxc) {
    int i = blockIdx.x * 256 + threadIdx.x;  // i = f*NN + n, f in [0,40)
    if (i >= 40 * NN) return;
    int f = i / NN, n = i - f * NN;
    int f2 = f + 40;
    float mu1 = bnst[f] * (1.f / NN);
    float ms1 = bnst[80 + f] * (1.f / NN);
    float v1 = (yT[(size_t)f * NN + n] - mu1) *
               (1.f / sqrtf(fmaxf(ms1 - mu1 * mu1, 0.f) + 1e-5f)) * gamma_l[f] + beta_l[f];
    v1 = fmaxf(v1, 0.f);
    float mu2 = bnst[f2] * (1.f / NN);
    float ms2 = bnst[80 + f2] * (1.f / NN);
    float v2 = (yT[(size_t)f2 * NN + n] - mu2) *
               (1.f / sqrtf(fmaxf(ms2 - mu2 * mu2, 0.f) + 1e-5f)) * gamma_l[f2] + beta_l[f2];
    v2 = fmaxf(v2, 0.f);
    lxc[(size_t)n * 40 + f] = logf(v1 * x[2 * n + 1] + v2 + 1e-6f);
}

// ---------------- tail kernels ----------------
__global__ void k_logagg(const float* __restrict__ lxc, const int* __restrict__ offs,
                         const int* __restrict__ csr, const int* __restrict__ batch,
                         float* __restrict__ pooled) {
    int n = blockIdx.x;
    int tid = threadIdx.x;  // 64
    if (tid >= 40) return;
    int e0 = offs[n], e1 = offs[n + 1];
    float s = 0.f;
    for (int k = e0; k < e1; ++k) s += lxc[(size_t)csr[k] * 40 + tid];
    float v = expf(s + lxc[(size_t)n * 40 + tid]);
    atomicAdd(&pooled[batch[n] * 40 + tid], v);
}

__global__ void k_final(const float* __restrict__ pooled, const int* __restrict__ gcnt,
                        const float* __restrict__ mlW, const float* __restrict__ mlb,
                        const float* __restrict__ m1W, const float* __restrict__ m1b,
                        const float* __restrict__ m2W, const float* __restrict__ m2b,
                        float* __restrict__ out) {
    int g = threadIdx.x;
    if (g >= NG) return;
    float inv = 1.f / fmaxf((float)gcnt[g], 1.f);
    float pl[40];
#pragma unroll
    for (int j = 0; j < 40; j++) pl[j] = pooled[g * 40 + j] * inv;
    float xl = mlb[0];
#pragma unroll
    for (int j = 0; j < 40; j++) xl += pl[j] * mlW[j];
    float acc = m2b[0];
    for (int k = 0; k < 20; k++) {
        float v = m1b[k];
#pragma unroll
        for (int j = 0; j < 40; j++) v += pl[j] * m1W[j * 20 + k];
        v = 20.f - fmaxf(v, 0.f);
        acc += v * m2W[k];
    }
    out[g] = acc + xl;
}

// ---------------- launcher ----------------
extern "C" void kernel_launch(void* const* d_in, const int* in_sizes, int n_in,
                              void* d_out, int out_size, void* d_ws, size_t ws_size,
                              hipStream_t stream) {
    const float* x     = (const float*)d_in[0];
    const int*   ei    = (const int*)d_in[1];
    const int*   batch = (const int*)d_in[2];
    const float* plW   = (const float*)d_in[3];
    const float* plb   = (const float*)d_in[4];
    const float* preW  = (const float*)d_in[5];
    const float* preb  = (const float*)d_in[6];
    const float* postW = (const float*)d_in[7];
    const float* postb = (const float*)d_in[8];
    const float* linW  = (const float*)d_in[9];
    const float* linb  = (const float*)d_in[10];
    const float* bnG   = (const float*)d_in[11];
    const float* bnB   = (const float*)d_in[12];
    const float* mlW   = (const float*)d_in[13];
    const float* mlb   = (const float*)d_in[14];
    const float* m1W   = (const float*)d_in[15];
    const float* m1b   = (const float*)d_in[16];
    const float* m2W   = (const float*)d_in[17];
    const float* m2b   = (const float*)d_in[18];
    float* out = (float*)d_out;
    const int* srcp = ei;
    const int* dstp = ei + NE;

    char* p = (char*)d_ws;
    int*   deg    = (int*)(p + 0);          // 40000 B (zeroed)
    int*   cursor = (int*)(p + 40000);      // 40000 B (zeroed)
    int*   gcnt   = (int*)(p + 80000);      // 256 B   (zeroed)
    float* ald    = (float*)(p + 80256);    // 16 B    (zeroed)
    float* pooled = (float*)(p + 80272);    // 10240 B (zeroed)
    float* bnst   = (float*)(p + 90512);    // 2560 B  (zeroed; atomic-accumulated)
    int*   offs   = (int*)(p + 93072);      // 40016 B
    int*   csr    = (int*)(p + 133088);     // 640000 B
    float* hT     = (float*)(p + 773088);   // 3.2 MB  [80][NN]      (live across layers)
    float* A      = (float*)(p + 3973088);  // 16 MB   [NN][400]
    float* Bt     = (float*)(p + 19973088); // 16 MB   [5][NN][80]
    // aggT is GONE (R7 fusion). Its old 64 MB region hosts the layer-local
    // buffers; Bt stays live through k_aggpost, so nothing may overlay it.
    float* y0T = (float*)(p + 35973088);    // 3.2 MB  [80][NN]  (k_aggpost direct-write)
    float* yT  = (float*)(p + 39173088);    // 3.2 MB  [80][NN]  (k_lin -> bn)
    float* lxc = (float*)(p + 42373088);    // 1.6 MB  [NN][40]  (tail)

    hipMemsetAsync(d_ws, 0, 93072, stream);
    k_cnt2<<<dim3((NE + 255) / 256), 256, 0, stream>>>(dstp, batch, deg, gcnt);
    k_scan<<<1, 256, 0, stream>>>(deg, offs);
    k_ald<<<dim3((NN + 255) / 256), 256, 0, stream>>>(deg, ald);
    k_fill<<<dim3((NE + 255) / 256), 256, 0, stream>>>(srcp, dstp, offs, cursor, csr);
    k_op0<<<dim3((FEAT * NN + 255) / 256), 256, 0, stream>>>(x, plW, plb, hT);

    for (int l = 0; l < NL; ++l) {
        const float* preW_l  = preW  + (size_t)l * NT * 160 * 80;
        const float* preb_l  = preb  + l * NT * 80;
        const float* postW_l = postW + (size_t)l * NT * 1040 * 16;
        const float* postb_l = postb + l * NT * 16;
        const float* linW_l  = linW  + l * 80 * 80;
        const float* linb_l  = linb  + l * 80;
        float* bnst_l = bnst + l * 160;
        k_mm_ab<<<dim3(625), 256, 0, stream>>>(hT, preW_l, A, Bt);
        k_aggpost<<<dim3(625, 5), 256, 0, stream>>>(A, Bt, offs, csr, preb_l,
                                                    hT, postW_l, postb_l, ald, y0T);
        k_lin<<<dim3(40, 10), 256, 0, stream>>>(y0T, linW_l, linb_l, yT);
        k_bnstats<<<dim3(80, 8), 256, 0, stream>>>(yT, bnst_l);
        if (l < NL - 1) {
            k_bn<<<dim3((FEAT * NN + 255) / 256), 256, 0, stream>>>(
                yT, bnst_l, bnG + l * 80, bnB + l * 80, hT);
        } else {
            k_bnxc<<<dim3((40 * NN + 255) / 256), 256, 0, stream>>>(
                yT, bnst_l, bnG + l * 80, bnB + l * 80, x, lxc);
        }
    }

    k_logagg<<<dim3(NN), 64, 0, stream>>>(lxc, offs, csr, batch, pooled);
    k_final<<<1, 64, 0, stream>>>(pooled, gcnt, mlW, mlb, m1W, m1b, m2W, m2b, out);
}

// Round 9
// 821.943 us; speedup vs baseline: 1.0667x; 1.0667x over previous
//
#include <hip/hip_runtime.h>
#include <math.h>

#define NN 10000
#define NE 160000
#define NG 64
#define FEAT 80
#define NT 5
#define NL 4

// ---------------- setup kernels ----------------
__global__ void k_cnt2(const int* __restrict__ dst, const int* __restrict__ batch,
                       int* __restrict__ deg, int* __restrict__ gcnt) {
    int e = blockIdx.x * 256 + threadIdx.x;
    if (e < NE) atomicAdd(&deg[dst[e]], 1);
    if (e < NN) atomicAdd(&gcnt[batch[e]], 1);
}

__global__ void k_scan(const int* __restrict__ deg, int* __restrict__ offs) {
    __shared__ int sums[256];
    int tid = threadIdx.x;
    int start = tid * 40, stop = min(start + 40, NN);
    int s = 0;
    for (int i = start; i < stop; ++i) s += deg[i];
    sums[tid] = s;
    __syncthreads();
    for (int off = 1; off < 256; off <<= 1) {
        int v = (tid >= off) ? sums[tid - off] : 0;
        __syncthreads();
        sums[tid] += v;
        __syncthreads();
    }
    int base = (tid == 0) ? 0 : sums[tid - 1];
    for (int i = start; i < stop; ++i) { offs[i] = base; base += deg[i]; }
    if (tid == 255) offs[NN] = sums[255];
}

__global__ void k_ald(const int* __restrict__ deg, float* __restrict__ ald) {
    __shared__ float red[256];
    int i = blockIdx.x * 256 + threadIdx.x;
    red[threadIdx.x] = (i < NN) ? logf((float)deg[i] + 1.0f) : 0.0f;
    __syncthreads();
    for (int s = 128; s > 0; s >>= 1) {
        if (threadIdx.x < s) red[threadIdx.x] += red[threadIdx.x + s];
        __syncthreads();
    }
    if (threadIdx.x == 0) atomicAdd(ald, red[0]);
}

__global__ void k_fill(const int* __restrict__ src, const int* __restrict__ dst,
                       const int* __restrict__ offs, int* __restrict__ cursor,
                       int* __restrict__ csr) {
    int e = blockIdx.x * 256 + threadIdx.x;
    if (e < NE) {
        int d = dst[e];
        int p = atomicAdd(&cursor[d], 1);
        csr[offs[d] + p] = src[e];
    }
}

// hT is feature-major: hT[f*NN + n]
__global__ void k_op0(const float* __restrict__ x, const float* __restrict__ plW,
                      const float* __restrict__ plb, float* __restrict__ hT) {
    int i = blockIdx.x * 256 + threadIdx.x;  // i = f*NN + n
    if (i < FEAT * NN) {
        int f = i / NN, n = i - f * NN;
        hT[i] = x[2 * n] * plW[f] + plb[f];
    }
}

// ---------------- per-layer kernels ----------------
// k_mm_ab v3 (R6-proven): 4 c-slots per thread, grid (625). 16 FMA per
// block-broadcast ds_read_b128.
__global__ __launch_bounds__(256) void k_mm_ab(
        const float* __restrict__ hT, const float* __restrict__ preW_l,
        float* __restrict__ A, float* __restrict__ Bt) {
    __shared__ float hs[16][80];
    int n0 = blockIdx.x * 16;
    int tid = threadIdx.x;
    for (int i = tid; i < 16 * 80; i += 256) {
        int nl = i & 15, f = i >> 4;
        hs[nl][f] = hT[(size_t)f * NN + n0 + nl];
    }
    __syncthreads();
    float acc[4][16];
#pragma unroll
    for (int s = 0; s < 4; s++)
#pragma unroll
        for (int i = 0; i < 16; i++) acc[s][i] = 0.f;
    const float* wp[4];
#pragma unroll
    for (int s = 0; s < 4; s++) {
        int c = tid + s * 256;
        int cs = (c < 800) ? c : 0;          // safe base for dead slots
        int part = (cs >= 400) ? 1 : 0;
        int cc = cs - part * 400;
        int t = cc / 80, o = cc - t * 80;
        wp[s] = preW_l + (size_t)(t * 160 + part * 80) * 80 + o;  // + f*80 per f
    }
    for (int fq = 0; fq < 80; fq += 4) {
        float w[4][4];
#pragma unroll
        for (int s = 0; s < 4; s++) {
            w[s][0] = wp[s][(fq + 0) * 80];
            w[s][1] = wp[s][(fq + 1) * 80];
            w[s][2] = wp[s][(fq + 2) * 80];
            w[s][3] = wp[s][(fq + 3) * 80];
        }
#pragma unroll
        for (int i = 0; i < 16; i++) {
            float4 hv = *(const float4*)&hs[i][fq];
#pragma unroll
            for (int s = 0; s < 4; s++) {
                acc[s][i] += hv.x * w[s][0] + hv.y * w[s][1] +
                             hv.z * w[s][2] + hv.w * w[s][3];
            }
        }
    }
#pragma unroll
    for (int s = 0; s < 4; s++) {
        int c = tid + s * 256;
        if (c < 800) {
            int part = (c >= 400) ? 1 : 0;
            int cc = c - part * 400;
            int t = cc / 80, o = cc - t * 80;
            if (part == 0) {
#pragma unroll
                for (int i = 0; i < 16; i++) A[(size_t)(n0 + i) * 400 + cc] = acc[s][i];
            } else {
#pragma unroll
                for (int i = 0; i < 16; i++)
                    Bt[((size_t)t * NN + n0 + i) * 80 + o] = acc[s][i];
            }
        }
    }
}

// k_aggpost v2 (R9): fusion with AMORTIZED weight reads. R8 diagnosis: phase 2
// issued 3.25M broadcast-redundant vmem loads (each 64B line read by 16 lanes)
// ~= 85us of issue time — same ~3M-read invariant that capped every k_post
// variant at 57-60us. Fix: thread = (ng=tid&3 node-quad, og=(tid>>2)&3 o-quad,
// js=tid>>4 j-slice); each weight float4 now feeds 4 nodes x 4 o = 16 FMA.
// Weights staged per 32-j tile into a 6.1KB LDS buffer (each float4 loaded
// once per block from global, coalesced). st read grabs 4 nodes (consecutive
// ni). js-partials (48 accs) reduced in 4 chunks of 12 via the dead st
// buffer; js==0 threads (tid<16) finalize c1/c2/bias and write y0T directly
// (no atomics, no memset). LDS 21.76+6.1 = 27.9KB -> 5 blocks/CU (~62% occ).
// Phase 1 gather verbatim from R4/R6-proven k_agg_t (XCD t-cluster remap).
__global__ __launch_bounds__(256) void k_aggpost(
        const float* __restrict__ A, const float* __restrict__ Bt,
        const int* __restrict__ offs, const int* __restrict__ csr,
        const float* __restrict__ preb_l, const float* __restrict__ hT,
        const float* __restrict__ postW_l, const float* __restrict__ postb_l,
        const float* __restrict__ ald_sum, float* __restrict__ y0T) {
    __shared__ float st[320 * 17];    // 21.76 KB; reduce buffer after phase 2 reads
    __shared__ float wbuf[32 * 48];   // 6.14 KB weight tile
    int tid = threadIdx.x;
    // ---- XCD remap: 3125 blocks = 5*391 + 3*390 ----
    int id = blockIdx.y * 625 + blockIdx.x;
    int xcd = id & 7;
    int slot = id >> 3;
    int base = (xcd <= 5) ? xcd * 391 : 5 * 391 + (xcd - 5) * 390;
    int r = base + slot;
    int t = r / 625;
    int n0 = (r - t * 625) * 16;
    // ---- phase 1: edge gather (proven k_agg_t body) ----
    int ni = tid >> 4;   // node within block
    int cl = tid & 15;   // c-lane
    int n = n0 + ni;
    int e0 = offs[n], e1 = offs[n + 1];
    const float* Bts = Bt + (size_t)t * NN * 80;
    float s[5], q[5], mn[5], mx[5];
#pragma unroll
    for (int k = 0; k < 5; k++) { s[k] = 0.f; q[k] = 0.f; mn[k] = 3.4e38f; mx[k] = -3.4e38f; }
    int e = e0;
    for (; e + 3 < e1; e += 4) {
        const float* br0 = Bts + (size_t)csr[e] * 80 + cl;
        const float* br1 = Bts + (size_t)csr[e + 1] * 80 + cl;
        const float* br2 = Bts + (size_t)csr[e + 2] * 80 + cl;
        const float* br3 = Bts + (size_t)csr[e + 3] * 80 + cl;
#pragma unroll
        for (int k = 0; k < 5; k++) {
            float b0 = br0[k * 16];
            float b1 = br1[k * 16];
            float b2 = br2[k * 16];
            float b3 = br3[k * 16];
            s[k] += (b0 + b1) + (b2 + b3);
            q[k] += (b0 * b0 + b1 * b1) + (b2 * b2 + b3 * b3);
            mn[k] = fminf(mn[k], fminf(fminf(b0, b1), fminf(b2, b3)));
            mx[k] = fmaxf(mx[k], fmaxf(fmaxf(b0, b1), fmaxf(b2, b3)));
        }
    }
    for (; e < e1; ++e) {
        const float* br = Bts + (size_t)csr[e] * 80 + cl;
#pragma unroll
        for (int k = 0; k < 5; k++) {
            float b = br[k * 16];
            s[k] += b; q[k] += b * b;
            mn[k] = fminf(mn[k], b); mx[k] = fmaxf(mx[k], b);
        }
    }
    int d = e1 - e0;
    float degf = (float)d;
    float cnt = fmaxf(degf, 1.f);
#pragma unroll
    for (int k = 0; k < 5; k++) {
        int c = cl + k * 16;
        float a = A[(size_t)n * 400 + t * 80 + c] + preb_l[t * 80 + c];
        float mean = (degf * a + s[k]) / cnt;
        float msq  = (degf * a * a + 2.f * a * s[k] + q[k]) / cnt;
        float sd = sqrtf(fmaxf(msq - mean * mean, 0.f) + 1e-5f);
        float mnr = (d > 0) ? a + mn[k] : 0.f;
        float mxr = (d > 0) ? a + mx[k] : 0.f;
        st[(0 * 80 + c) * 17 + ni] = mean;
        st[(1 * 80 + c) * 17 + ni] = mnr;
        st[(2 * 80 + c) * 17 + ni] = mxr;
        st[(3 * 80 + c) * 17 + ni] = sd;
    }
    __syncthreads();
    // ---- phase 2: post-GEMM, amortized ----
    int ng = tid & 3;          // node quad: nodes n0 + ng*4 .. +3
    int og = (tid >> 2) & 3;   // o quad: o = og*4 .. +3
    int js = tid >> 4;         // j slice
    const float* W0 = postW_l + (size_t)t * 1040 * 16;
    float af[48];              // [p(3)][node(4)][o(4)] flattened: p*16 + i*4 + qo
#pragma unroll
    for (int k = 0; k < 48; k++) af[k] = 0.f;
    // j tiles: 10 tiles x 32 j; each thread: 2 j per tile (j_loc = js*2 + jl)
    for (int tile = 0; tile < 10; ++tile) {
        for (int idx4 = tid; idx4 < 384; idx4 += 256) {
            int j_loc = idx4 / 12;
            int rem = idx4 - j_loc * 12;
            int p = rem >> 2, o4 = rem & 3;
            int pofs = (p == 0) ? 80 : (p == 1) ? 400 : 720;
            int jg = tile * 32 + j_loc;
            *(float4*)&wbuf[j_loc * 48 + p * 16 + o4 * 4] =
                *(const float4*)(W0 + (size_t)(pofs + jg) * 16 + o4 * 4);
        }
        __syncthreads();
#pragma unroll
        for (int jl = 0; jl < 2; ++jl) {
            int j_loc = js * 2 + jl;
            int jg = tile * 32 + j_loc;
            const float* sp = st + jg * 17 + ng * 4;
            float s0 = sp[0], s1 = sp[1], s2 = sp[2], s3 = sp[3];
#pragma unroll
            for (int p = 0; p < 3; ++p) {
                float4 w = *(const float4*)&wbuf[j_loc * 48 + p * 16 + og * 4];
                af[p * 16 + 0 * 4 + 0] += s0 * w.x; af[p * 16 + 0 * 4 + 1] += s0 * w.y;
                af[p * 16 + 0 * 4 + 2] += s0 * w.z; af[p * 16 + 0 * 4 + 3] += s0 * w.w;
                af[p * 16 + 1 * 4 + 0] += s1 * w.x; af[p * 16 + 1 * 4 + 1] += s1 * w.y;
                af[p * 16 + 1 * 4 + 2] += s1 * w.z; af[p * 16 + 1 * 4 + 3] += s1 * w.w;
                af[p * 16 + 2 * 4 + 0] += s2 * w.x; af[p * 16 + 2 * 4 + 1] += s2 * w.y;
                af[p * 16 + 2 * 4 + 2] += s2 * w.z; af[p * 16 + 2 * 4 + 3] += s2 * w.w;
                af[p * 16 + 3 * 4 + 0] += s3 * w.x; af[p * 16 + 3 * 4 + 1] += s3 * w.y;
                af[p * 16 + 3 * 4 + 2] += s3 * w.z; af[p * 16 + 3 * 4 + 3] += s3 * w.w;
            }
        }
        __syncthreads();
    }
    // h-part: 5 tiles x 16 f; thread's f = ht*16 + js; contributes into p=0 accs
    for (int ht = 0; ht < 5; ++ht) {
        if (tid < 64) {
            int f_loc = tid >> 2, o4 = tid & 3;
            int fg = ht * 16 + f_loc;
            *(float4*)&wbuf[f_loc * 16 + o4 * 4] =
                *(const float4*)(W0 + (size_t)fg * 16 + o4 * 4);
        }
        __syncthreads();
        int fg = ht * 16 + js;
        float4 hv = *(const float4*)&hT[(size_t)fg * NN + n0 + ng * 4];
        float4 w = *(const float4*)&wbuf[js * 16 + og * 4];
        af[0 * 4 + 0] += hv.x * w.x; af[0 * 4 + 1] += hv.x * w.y;
        af[0 * 4 + 2] += hv.x * w.z; af[0 * 4 + 3] += hv.x * w.w;
        af[1 * 4 + 0] += hv.y * w.x; af[1 * 4 + 1] += hv.y * w.y;
        af[1 * 4 + 2] += hv.y * w.z; af[1 * 4 + 3] += hv.y * w.w;
        af[2 * 4 + 0] += hv.z * w.x; af[2 * 4 + 1] += hv.z * w.y;
        af[2 * 4 + 2] += hv.z * w.z; af[2 * 4 + 3] += hv.z * w.w;
        af[3 * 4 + 0] += hv.w * w.x; af[3 * 4 + 1] += hv.w * w.y;
        af[3 * 4 + 2] += hv.w * w.z; af[3 * 4 + 3] += hv.w * w.w;
        __syncthreads();
    }
    // ---- js reduction: 4 chunks of 12 floats via dead st ----
    float* red = st;
#pragma unroll
    for (int c = 0; c < 4; ++c) {
#pragma unroll
        for (int k = 0; k < 12; ++k) red[tid * 12 + k] = af[c * 12 + k];
        __syncthreads();
        if (js == 0) {
            for (int js2 = 1; js2 < 16; ++js2) {
                const float* rr = red + (size_t)(ng + (og << 2) + (js2 << 4)) * 12;
#pragma unroll
                for (int k = 0; k < 12; ++k) af[c * 12 + k] += rr[k];
            }
        }
        __syncthreads();
    }
    // ---- finalize (tid < 16: ng, og) ----
    if (js == 0) {
        float ald = ald_sum[0] * (1.f / NN);
        float v[4][4];   // [node][o]
#pragma unroll
        for (int i = 0; i < 4; ++i) {
            int nw = n0 + ng * 4 + i;
            float dw = (float)(offs[nw + 1] - offs[nw]);
            float logd = logf(fmaxf(dw, 1.f) + 1.f);
            float c1 = logd / ald;
            float c2 = ald / logd;
#pragma unroll
            for (int qo = 0; qo < 4; ++qo) {
                int o = og * 4 + qo;
                v[i][qo] = af[0 + i * 4 + qo] + c1 * af[16 + i * 4 + qo] +
                           c2 * af[32 + i * 4 + qo] + postb_l[t * 16 + o];
            }
        }
#pragma unroll
        for (int qo = 0; qo < 4; ++qo) {
            int o = og * 4 + qo;
            float4 pack = make_float4(v[0][qo], v[1][qo], v[2][qo], v[3][qo]);
            *(float4*)&y0T[(size_t)(t * 16 + o) * NN + n0 + ng * 4] = pack;
        }
    }
}

// k_lin v2 (R8-proven): grid (40, 10), 8 f per block, weights LDS-staged.
__global__ __launch_bounds__(256) void k_lin(
        const float* __restrict__ y0T, const float* __restrict__ linW_l,
        const float* __restrict__ linb_l, float* __restrict__ yT) {
    __shared__ float ws[80 * 8];  // 2.56 KB
    int tid = threadIdx.x;
    int f0 = blockIdx.y * 8;
    for (int idx = tid; idx < 80 * 8; idx += 256)
        ws[idx] = linW_l[(idx >> 3) * 80 + f0 + (idx & 7)];
    __syncthreads();
    int n = blockIdx.x * 256 + tid;
    bool alive = (n < NN);
    int nc = alive ? n : 0;
    float acc[8];
#pragma unroll
    for (int i = 0; i < 8; i++) acc[i] = 0.f;
#pragma unroll 8
    for (int k = 0; k < 80; ++k) {
        float v = y0T[(size_t)k * NN + nc];
        const float4 wa = *(const float4*)(ws + k * 8);
        const float4 wb = *(const float4*)(ws + k * 8 + 4);
        acc[0] += v * wa.x; acc[1] += v * wa.y; acc[2] += v * wa.z; acc[3] += v * wa.w;
        acc[4] += v * wb.x; acc[5] += v * wb.y; acc[6] += v * wb.z; acc[7] += v * wb.w;
    }
    if (alive) {
#pragma unroll
        for (int i = 0; i < 8; i++)
            yT[(size_t)(f0 + i) * NN + n] = acc[i] + linb_l[f0 + i];
    }
}

// k_bnstats v2: grid (80, 8).
__global__ void k_bnstats(const float* __restrict__ yT, float* __restrict__ bnst) {
    __shared__ float r1[256], r2[256];
    int f = blockIdx.x;
    int seg = blockIdx.y;
    int tid = threadIdx.x;
    int i0 = seg * 1250, i1 = min(i0 + 1250, NN);
    float s = 0.f, q = 0.f;
    for (int i = i0 + tid; i < i1; i += 256) {
        float v = yT[(size_t)f * NN + i];
        s += v; q += v * v;
    }
    r1[tid] = s; r2[tid] = q;
    __syncthreads();
    for (int st = 128; st > 0; st >>= 1) {
        if (tid < st) { r1[tid] += r1[tid + st]; r2[tid] += r2[tid + st]; }
        __syncthreads();
    }
    if (tid == 0) {
        unsafeAtomicAdd(&bnst[f], r1[0]);
        unsafeAtomicAdd(&bnst[80 + f], r2[0]);
    }
}

__global__ void k_bn(const float* __restrict__ yT, const float* __restrict__ bnst,
                     const float* __restrict__ gamma_l, const float* __restrict__ beta_l,
                     float* __restrict__ hT) {
    int i = blockIdx.x * 256 + threadIdx.x;
    if (i >= FEAT * NN) return;
    int f = i / NN;
    float mu = bnst[f] * (1.f / NN);
    float msq = bnst[80 + f] * (1.f / NN);
    float var = fmaxf(msq - mu * mu, 0.f);
    float v = (yT[i] - mu) * (1.f / sqrtf(var + 1e-5f)) * gamma_l[f] + beta_l[f];
    hT[i] = fmaxf(v, 0.f);
}

__global__ void k_bnxc(const float* __restrict__ yT, const float* __restrict__ bnst,
                       const float* __restrict__ gamma_l, const float* __restrict__ beta_l,
                       const float* __restrict__ x, float* __restrict__ lxc) {
    int i = blockIdx.x * 256 + threadIdx.x;  // i = f*NN + n, f in [0,40)
    if (i >= 40 * NN) return;
    int f = i / NN, n = i - f * NN;
    int f2 = f + 40;
    float mu1 = bnst[f] * (1.f / NN);
    float ms1 = bnst[80 + f] * (1.f / NN);
    float v1 = (yT[(size_t)f * NN + n] - mu1) *
               (1.f / sqrtf(fmaxf(ms1 - mu1 * mu1, 0.f) + 1e-5f)) * gamma_l[f] + beta_l[f];
    v1 = fmaxf(v1, 0.f);
    float mu2 = bnst[f2] * (1.f / NN);
    float ms2 = bnst[80 + f2] * (1.f / NN);
    float v2 = (yT[(size_t)f2 * NN + n] - mu2) *
               (1.f / sqrtf(fmaxf(ms2 - mu2 * mu2, 0.f) + 1e-5f)) * gamma_l[f2] + beta_l[f2];
    v2 = fmaxf(v2, 0.f);
    lxc[(size_t)n * 40 + f] = logf(v1 * x[2 * n + 1] + v2 + 1e-6f);
}

// ---------------- tail kernels ----------------
__global__ void k_logagg(const float* __restrict__ lxc, const int* __restrict__ offs,
                         const int* __restrict__ csr, const int* __restrict__ batch,
                         float* __restrict__ pooled) {
    int n = blockIdx.x;
    int tid = threadIdx.x;  // 64
    if (tid >= 40) return;
    int e0 = offs[n], e1 = offs[n + 1];
    float s = 0.f;
    for (int k = e0; k < e1; ++k) s += lxc[(size_t)csr[k] * 40 + tid];
    float v = expf(s + lxc[(size_t)n * 40 + tid]);
    atomicAdd(&pooled[batch[n] * 40 + tid], v);
}

__global__ void k_final(const float* __restrict__ pooled, const int* __restrict__ gcnt,
                        const float* __restrict__ mlW, const float* __restrict__ mlb,
                        const float* __restrict__ m1W, const float* __restrict__ m1b,
                        const float* __restrict__ m2W, const float* __restrict__ m2b,
                        float* __restrict__ out) {
    int g = threadIdx.x;
    if (g >= NG) return;
    float inv = 1.f / fmaxf((float)gcnt[g], 1.f);
    float pl[40];
#pragma unroll
    for (int j = 0; j < 40; j++) pl[j] = pooled[g * 40 + j] * inv;
    float xl = mlb[0];
#pragma unroll
    for (int j = 0; j < 40; j++) xl += pl[j] * mlW[j];
    float acc = m2b[0];
    for (int k = 0; k < 20; k++) {
        float v = m1b[k];
#pragma unroll
        for (int j = 0; j < 40; j++) v += pl[j] * m1W[j * 20 + k];
        v = 20.f - fmaxf(v, 0.f);
        acc += v * m2W[k];
    }
    out[g] = acc + xl;
}

// ---------------- launcher ----------------
extern "C" void kernel_launch(void* const* d_in, const int* in_sizes, int n_in,
                              void* d_out, int out_size, void* d_ws, size_t ws_size,
                              hipStream_t stream) {
    const float* x     = (const float*)d_in[0];
    const int*   ei    = (const int*)d_in[1];
    const int*   batch = (const int*)d_in[2];
    const float* plW   = (const float*)d_in[3];
    const float* plb   = (const float*)d_in[4];
    const float* preW  = (const float*)d_in[5];
    const float* preb  = (const float*)d_in[6];
    const float* postW = (const float*)d_in[7];
    const float* postb = (const float*)d_in[8];
    const float* linW  = (const float*)d_in[9];
    const float* linb  = (const float*)d_in[10];
    const float* bnG   = (const float*)d_in[11];
    const float* bnB   = (const float*)d_in[12];
    const float* mlW   = (const float*)d_in[13];
    const float* mlb   = (const float*)d_in[14];
    const float* m1W   = (const float*)d_in[15];
    const float* m1b   = (const float*)d_in[16];
    const float* m2W   = (const float*)d_in[17];
    const float* m2b   = (const float*)d_in[18];
    float* out = (float*)d_out;
    const int* srcp = ei;
    const int* dstp = ei + NE;

    char* p = (char*)d_ws;
    int*   deg    = (int*)(p + 0);          // 40000 B (zeroed)
    int*   cursor = (int*)(p + 40000);      // 40000 B (zeroed)
    int*   gcnt   = (int*)(p + 80000);      // 256 B   (zeroed)
    float* ald    = (float*)(p + 80256);    // 16 B    (zeroed)
    float* pooled = (float*)(p + 80272);    // 10240 B (zeroed)
    float* bnst   = (float*)(p + 90512);    // 2560 B  (zeroed; atomic-accumulated)
    int*   offs   = (int*)(p + 93072);      // 40016 B
    int*   csr    = (int*)(p + 133088);     // 640000 B
    float* hT     = (float*)(p + 773088);   // 3.2 MB  [80][NN]      (live across layers)
    float* A      = (float*)(p + 3973088);  // 16 MB   [NN][400]
    float* Bt     = (float*)(p + 19973088); // 16 MB   [5][NN][80]
    // aggT eliminated (R7/R9 fusion). Bt stays live through k_aggpost; layer
    // buffers live past its old region.
    float* y0T = (float*)(p + 35973088);    // 3.2 MB  [80][NN]  (k_aggpost direct-write)
    float* yT  = (float*)(p + 39173088);    // 3.2 MB  [80][NN]  (k_lin -> bn)
    float* lxc = (float*)(p + 42373088);    // 1.6 MB  [NN][40]  (tail)

    hipMemsetAsync(d_ws, 0, 93072, stream);
    k_cnt2<<<dim3((NE + 255) / 256), 256, 0, stream>>>(dstp, batch, deg, gcnt);
    k_scan<<<1, 256, 0, stream>>>(deg, offs);
    k_ald<<<dim3((NN + 255) / 256), 256, 0, stream>>>(deg, ald);
    k_fill<<<dim3((NE + 255) / 256), 256, 0, stream>>>(srcp, dstp, offs, cursor, csr);
    k_op0<<<dim3((FEAT * NN + 255) / 256), 256, 0, stream>>>(x, plW, plb, hT);

    for (int l = 0; l < NL; ++l) {
        const float* preW_l  = preW  + (size_t)l * NT * 160 * 80;
        const float* preb_l  = preb  + l * NT * 80;
        const float* postW_l = postW + (size_t)l * NT * 1040 * 16;
        const float* postb_l = postb + l * NT * 16;
        const float* linW_l  = linW  + l * 80 * 80;
        const float* linb_l  = linb  + l * 80;
        float* bnst_l = bnst + l * 160;
        k_mm_ab<<<dim3(625), 256, 0, stream>>>(hT, preW_l, A, Bt);
        k_aggpost<<<dim3(625, 5), 256, 0, stream>>>(A, Bt, offs, csr, preb_l,
                                                    hT, postW_l, postb_l, ald, y0T);
        k_lin<<<dim3(40, 10), 256, 0, stream>>>(y0T, linW_l, linb_l, yT);
        k_bnstats<<<dim3(80, 8), 256, 0, stream>>>(yT, bnst_l);
        if (l < NL - 1) {
            k_bn<<<dim3((FEAT * NN + 255) / 256), 256, 0, stream>>>(
                yT, bnst_l, bnG + l * 80, bnB + l * 80, hT);
        } else {
            k_bnxc<<<dim3((40 * NN + 255) / 256), 256, 0, stream>>>(
                yT, bnst_l, bnG + l * 80, bnB + l * 80, x, lxc);
        }
    }

    k_logagg<<<dim3(NN), 64, 0, stream>>>(lxc, offs, csr, batch, pooled);
    k_final<<<1, 64, 0, stream>>>(pooled, gcnt, mlW, mlb, m1W, m1b, m2W, m2b, out);
}